// Round 8
// baseline (208.456 us; speedup 1.0000x reference)
//
#include <hip/hip_runtime.h>
#include <cstdint>

#define B_      32
#define N_      32768
#define C_      81
#define NCLS    80      // last class (background) skipped
#define TOPK    200
#define CONF_T  0.01f
#define IOU_T   0.45f
#define NTH     256
#define NBC     (B_ * NCLS)          // 2560 (b,c) tasks

// exact IoU threshold compare without div:
// fl(inter/U) > 0.45f  <=>  (double)inter > M_IOU * (double)U   (U >= 0)
#define M_IOU   0.450000017881393432617187500

// ---- fast-path pre-filter: THR = 1 - 2^-6 = 0.984375 ----
#define THR_F    0.984375f
#define THR_BITS 0x3F7C0000u
#define CAP2     768

// filter blocking: one block per (b, 512-anchor slab)
#define ANCH_PB  512
#define NCHUNK   (N_ / ANCH_PB)      // 64
#define SLAB_F4  (ANCH_PB * C_ / 4)  // 10368 float4 per block
#define CAPB     1024

// slow-path histogram buckets over [0.5,1.0) via float bits
#define HBASE   129024
#define HBUCK   1024

// ws layout (bytes): cnt[NBC] | qn | qbuf[NBC] | cand[NBC][CAP2] uint2
#define OFF_CNT   0
#define OFF_QN    12288
#define OFF_QBUF  16384
#define OFF_CAND  32768
#define WS_NEED  (OFF_CAND + (size_t)NBC * CAP2 * 8)

__global__ void zero_hdr(int* __restrict__ p) {      // zeros cnt + qn
    int i = blockIdx.x * blockDim.x + threadIdx.x;
    if (i < 4096) p[i] = 0;
}

// ---- filter: at HBM roofline, frozen since R4 ----
__global__ __launch_bounds__(NTH) void filter_k(const float* __restrict__ conf,
                                                int* __restrict__ cnt,
                                                uint2* __restrict__ cand) {
    const int tid   = threadIdx.x;
    const int blk   = blockIdx.x;
    const int b     = blk >> 6;
    const int chunk = blk & (NCHUNK - 1);
    const uint32_t n0 = (uint32_t)chunk * ANCH_PB;
    const float4* slab = (const float4*)(conf + ((size_t)b * N_ + n0) * C_);

    __shared__ uint2 stage[CAPB];
    __shared__ int   lhist[NCLS];
    __shared__ int   lpos[NCLS];
    __shared__ int   gbase[NCLS];
    __shared__ int   ltot;

    for (int k = tid; k < NCLS; k += NTH) { lhist[k] = 0; lpos[k] = 0; }
    if (tid == 0) ltot = 0;
    __syncthreads();

    auto emit = [&](uint32_t e, float v) {
        uint32_t c = e % (uint32_t)C_;
        if (c < NCLS) {
            uint32_t nl = e / (uint32_t)C_;
            int q = atomicAdd(&ltot, 1);
            atomicAdd(&lhist[c], 1);
            if (q < CAPB)
                stage[q] = make_uint2(__float_as_uint(v), (c << 16) | nl);
        }
    };
    auto proc4 = [&](float4 x, uint32_t q) {
        if (x.x >= THR_F || x.y >= THR_F || x.z >= THR_F || x.w >= THR_F) {
            uint32_t e = q * 4u;
            if (x.x >= THR_F) emit(e + 0u, x.x);
            if (x.y >= THR_F) emit(e + 1u, x.y);
            if (x.z >= THR_F) emit(e + 2u, x.z);
            if (x.w >= THR_F) emit(e + 3u, x.w);
        }
    };

    uint32_t qb = (uint32_t)tid;
#pragma unroll 1
    for (int s = 0; s < 5; ++s, qb += 8 * NTH) {
        float4 v[8];
#pragma unroll
        for (int u = 0; u < 8; ++u) v[u] = slab[qb + u * NTH];
#pragma unroll
        for (int u = 0; u < 8; ++u) proc4(v[u], qb + u * NTH);
    }
    if (tid < SLAB_F4 - 5 * 8 * NTH) {
        uint32_t q = 5u * 8u * NTH + (uint32_t)tid;
        proc4(slab[q], q);
    }
    __syncthreads();

    const int tot = ltot;
    if (tot > CAPB) {
        for (int k = tid; k < NCLS; k += NTH)
            atomicAdd(&cnt[b * NCLS + k], CAP2 + 1);
        return;
    }
    if (tid < NCLS)
        gbase[tid] = atomicAdd(&cnt[b * NCLS + tid], lhist[tid]);
    __syncthreads();

    for (int q = tid; q < tot; q += NTH) {
        uint2 s = stage[q];
        uint32_t c  = s.y >> 16;
        uint32_t nl = s.y & 0xFFFFu;
        int pos = atomicAdd(&lpos[c], 1);
        int dst = gbase[c] + pos;
        if (dst < CAP2)
            cand[(size_t)(b * NCLS + c) * CAP2 + dst] = make_uint2(s.x, n0 + nl);
    }
}

// ---- select LDS: phase-disjoint overlays (16848 B -> 8 blocks/CU) ----
// region A [0,8000):    surv u64-key[768] -> sup u64[200][5] -> ostage f32[1200]
// region B [8000,14400): hist int[256|1024] -> box f4[200] + cor f4[200]
#define SUPS      5
#define SM_A      0
#define SM_B      8000
#define SM_BOX    8000
#define SM_COR    11200
#define SM_TVAL   14400
#define SM_TIDX   15200
#define SM_CTRL   16000
#define SM_KEEPW  16016
#define SM_AREA   16048
#define SM_TOTAL  16848

// fast-path only; punts to queue. 4 waves split every heavy phase.
__global__ __launch_bounds__(NTH) void select_nms_k(const float* __restrict__ loc,
                                                    const int* __restrict__ cnt,
                                                    const uint2* __restrict__ cand,
                                                    int* __restrict__ qn,
                                                    int* __restrict__ qbuf,
                                                    float* __restrict__ out) {
#pragma clang fp contract(off)
    const int bc   = blockIdx.x;
    const int b    = bc / NCLS;
    const int c    = bc - b * NCLS;
    const int tid  = threadIdx.x;
    const int lane = tid & 63;
    const int wv   = tid >> 6;

    const int M = cnt[bc];
    if (M < TOPK || M > CAP2) {                    // punt -> rescue queue
        if (tid == 0) { int p = atomicAdd(qn, 1); qbuf[p] = bc; }
        return;
    }

    __shared__ __align__(16) char smem[SM_TOTAL];
    unsigned long long* surv = (unsigned long long*)(smem + SM_A);
    unsigned long long* sup  = (unsigned long long*)(smem + SM_A);
    float*  ostage = (float*)(smem + SM_A);
    int*    hist   = (int*)(smem + SM_B);
    float4* box_s  = (float4*)(smem + SM_BOX);
    float4* cor_s  = (float4*)(smem + SM_COR);
    float*  top_val = (float*)(smem + SM_TVAL);
    int*    top_idx = (int*)(smem + SM_TIDX);
    int*    ctrl   = (int*)(smem + SM_CTRL);
    unsigned long long* keepw = (unsigned long long*)(smem + SM_KEEPW);
    float*  area_s = (float*)(smem + SM_AREA);

    // phase 1: candidates -> registers; zero hist
    const uint2* src = cand + (size_t)bc * CAP2;
    uint2 my0 = make_uint2(0u, 0u), my1 = make_uint2(0u, 0u), my2 = make_uint2(0u, 0u);
    if (tid           < M) my0 = src[tid];
    if (tid +     NTH < M) my1 = src[tid + NTH];
    if (tid + 2 * NTH < M) my2 = src[tid + 2 * NTH];
    hist[tid] = 0;
    if (tid == 0) ctrl[2] = 0;
    __syncthreads();

    // phase 2: 256-bucket histogram
    if (tid           < M) { uint32_t k = (my0.x - THR_BITS) >> 10; atomicAdd(&hist[k > 255u ? 255u : k], 1); }
    if (tid +     NTH < M) { uint32_t k = (my1.x - THR_BITS) >> 10; atomicAdd(&hist[k > 255u ? 255u : k], 1); }
    if (tid + 2 * NTH < M) { uint32_t k = (my2.x - THR_BITS) >> 10; atomicAdd(&hist[k > 255u ? 255u : k], 1); }
    __syncthreads();

    // phase 3: wave-0 suffix scan for cutoff bucket
    if (tid < 64) {
        int4 h = ((const int4*)hist)[63 - tid];
        int s3 = h.w, s2 = s3 + h.z, s1 = s2 + h.y, s0 = s1 + h.x;
        int tot = s0;
#pragma unroll
        for (int d = 1; d < 64; d <<= 1) {
            int t = __shfl_up(tot, d);
            if (tid >= d) tot += t;
        }
        int before = tot - s0;
        if (before < TOPK && before + s0 >= TOPK) {
            int inner = (before + s3 >= TOPK) ? 3 : (before + s2 >= TOPK) ? 2
                      : (before + s1 >= TOPK) ? 1 : 0;
            ctrl[1] = (63 - tid) * 4 + inner;
        }
    }
    __syncthreads();

    // phase 4: ballot-compact survivors (u64 keys)
    const uint32_t edge = THR_BITS + ((uint32_t)ctrl[1] << 10);
#define COMPACT(MY)                                                          \
    {                                                                        \
        bool take = (MY.x >= edge);                                          \
        unsigned long long mask = __ballot(take);                            \
        int base = 0;                                                        \
        if (lane == 0 && mask) base = atomicAdd(&ctrl[2], (int)__popcll(mask)); \
        base = __shfl(base, 0);                                              \
        if (take) {                                                          \
            int pos = base + (int)__popcll(mask & ((1ull << lane) - 1ull));  \
            if (pos < CAP2)                                                  \
                surv[pos] = ((unsigned long long)MY.x << 32) | (uint32_t)(~MY.y); \
        }                                                                    \
    }
    COMPACT(my0) COMPACT(my1) COMPACT(my2)
#undef COMPACT
    __syncthreads();
    const int S = min(ctrl[2], CAP2);              // >= TOPK by cutoff choice

    // phase 5: exact rank (u64: val desc, idx asc) + fused loc gather
    for (int i = tid; i < S; i += NTH) {
        unsigned long long me = surv[i];
        int rank = 0;
#pragma unroll 4
        for (int j = 0; j < S; ++j)
            rank += (surv[j] > me);
        if (rank < TOPK) {
            int idx = (int)(~(uint32_t)me);
            top_val[rank] = __uint_as_float((uint32_t)(me >> 32));
            top_idx[rank] = idx;
            float4 bx = *(const float4*)(loc + ((size_t)b * N_ + (size_t)idx) * 4);
            float hw = bx.z * 0.5f;
            float hh = bx.w * 0.5f;
            float4 cr = make_float4(bx.x - hw, bx.y - hh, bx.x + hw, bx.y + hh);
            box_s[rank] = bx;
            cor_s[rank] = cr;
            area_s[rank] = (cr.z - cr.x) * (cr.w - cr.y);
        }
    }
    __syncthreads();                               // surv dead; sup overlays A

    {   // keep-init (all ranks filled since S >= TOPK)
        bool v = (tid < TOPK);
        unsigned long long m = __ballot(v);
        if (lane == 0) keepw[wv] = m;
    }

    {   // sup matrix: wave w owns column word w; 200 ballots per wave
        const int j = tid;
        float4 d = make_float4(0.f, 0.f, 0.f, 0.f);
        float  areaB = 0.0f;
        const bool jv = (j < TOPK);
        if (jv) { d = cor_s[j]; areaB = area_s[j]; }
#pragma unroll 2
        for (int i = 0; i < TOPK; ++i) {
            float4 a = cor_s[i];
            bool s = false;
            if (jv && j > i) {
                float ltx = fmaxf(a.x, d.x), lty = fmaxf(a.y, d.y);
                float rbx = fminf(a.z, d.z), rby = fminf(a.w, d.w);
                float w  = fmaxf(rbx - ltx, 0.0f);
                float h  = fmaxf(rby - lty, 0.0f);
                float inter = w * h;
                float U = (area_s[i] + areaB) - inter;
                s = ((double)inter > M_IOU * (double)U);
            }
            unsigned long long m = __ballot(s);
            if (lane == 0) sup[i * SUPS + wv] = m;
        }
    }
    __syncthreads();

    // greedy scan in wave 0 registers (latency-only, hidden by other blocks)
    if (tid < 64) {
        unsigned long long r0[4], r1[4], r2[4], r3[4];
#pragma unroll
        for (int w = 0; w < 4; ++w) {
            r0[w] = sup[(0 * 64 + tid) * SUPS + w];
            r1[w] = sup[(1 * 64 + tid) * SUPS + w];
            r2[w] = sup[(2 * 64 + tid) * SUPS + w];
            r3[w] = (192 + tid < TOPK) ? sup[(192 + tid) * SUPS + w] : 0ull;
        }
        unsigned long long k0 = keepw[0], k1 = keepw[1], k2 = keepw[2], k3 = keepw[3];
#define GREEDY_BLK(KW, RR)                                            \
        for (int ii = 0; ii < 64; ++ii) {                             \
            if ((KW >> ii) & 1ull) {                                  \
                k0 &= ~__shfl(RR[0], ii);                             \
                k1 &= ~__shfl(RR[1], ii);                             \
                k2 &= ~__shfl(RR[2], ii);                             \
                k3 &= ~__shfl(RR[3], ii);                             \
            }                                                         \
        }
        GREEDY_BLK(k0, r0)
        GREEDY_BLK(k1, r1)
        GREEDY_BLK(k2, r2)
        GREEDY_BLK(k3, r3)
#undef GREEDY_BLK
        if (tid == 0) { keepw[0] = k0; keepw[1] = k1; keepw[2] = k2; keepw[3] = k3; }
    }
    __syncthreads();                               // sup dead; ostage overlays A

    if (tid < TOPK) {
        const bool kp = (keepw[tid >> 6] >> (tid & 63)) & 1ull;
        float4 bx = box_s[tid];
        float* o = ostage + tid * 6;
        if (kp) {
            o[0] = (float)c;   o[1] = top_val[tid];
            o[2] = bx.x; o[3] = bx.y; o[4] = bx.z; o[5] = bx.w;
        } else {
            o[0] = -1.f; o[1] = -1.f; o[2] = -1.f;
            o[3] = -1.f; o[4] = -1.f; o[5] = -1.f;
        }
        out[(size_t)NBC * TOPK * 6 + (size_t)bc * TOPK + tid] = kp ? 1.0f : 0.0f;
    }
    __syncthreads();
    {
        float4* dst = (float4*)(out + (size_t)bc * TOPK * 6);
        const float4* src4 = (const float4*)ostage;
        for (int k = tid; k < TOPK * 6 / 4; k += NTH) dst[k] = src4[k];
    }
}

// ---- rescue: slow path only (punted / no-ws tasks), queue- or grid-driven ----
__global__ __launch_bounds__(NTH) void rescue_k(const float* __restrict__ conf,
                                                const float* __restrict__ loc,
                                                const int* __restrict__ qn,
                                                const int* __restrict__ qbuf,
                                                float* __restrict__ out,
                                                int qmode) {
#pragma clang fp contract(off)
    const int tid  = threadIdx.x;
    const int lane = tid & 63;
    const int wv   = tid >> 6;
    const int niter = qmode ? *qn : NBC;

    __shared__ __align__(16) char smem[SM_TOTAL];
    unsigned long long* surv = (unsigned long long*)(smem + SM_A);
    unsigned long long* sup  = (unsigned long long*)(smem + SM_A);
    float*  ostage = (float*)(smem + SM_A);
    int*    hist   = (int*)(smem + SM_B);
    float4* box_s  = (float4*)(smem + SM_BOX);
    float4* cor_s  = (float4*)(smem + SM_COR);
    float*  top_val = (float*)(smem + SM_TVAL);
    int*    top_idx = (int*)(smem + SM_TIDX);
    int*    ctrl   = (int*)(smem + SM_CTRL);
    unsigned long long* keepw = (unsigned long long*)(smem + SM_KEEPW);
    float*  area_s = (float*)(smem + SM_AREA);

    for (int qi = blockIdx.x; qi < niter; qi += gridDim.x) {
        const int bc = qmode ? qbuf[qi] : qi;
        const int b  = bc / NCLS;
        const int c  = bc - b * NCLS;

        for (int k = tid; k < HBUCK; k += NTH) hist[k] = 0;
        if (tid == 0) ctrl[2] = 0;
        __syncthreads();
        const float* col = conf + ((size_t)b * N_) * C_ + c;
        for (int n = tid; n < N_; n += NTH) {
            float v = col[(size_t)n * C_];
            if (v >= 0.5f) {
                int bkt = (int)(__float_as_uint(v) >> 13) - HBASE;
                atomicAdd(&hist[min(bkt, HBUCK - 1)], 1);
            }
        }
        __syncthreads();
        if (tid == 0) {
            int acc = 0, cut = -1;
            for (int k = HBUCK - 1; k >= 0; --k) {
                acc += hist[k];
                if (acc >= TOPK) { cut = k; break; }
            }
            ctrl[1] = cut;
        }
        __syncthreads();
        const int   cutv = ctrl[1];
        const float vcut = (cutv >= 0) ? __uint_as_float((uint32_t)(HBASE + cutv) << 13)
                                       : CONF_T;
        for (int n = tid; n < N_; n += NTH) {
            float v = col[(size_t)n * C_];
            bool take = (cutv >= 0) ? (v >= vcut) : (v > CONF_T);
            if (take) {
                int p = atomicAdd(&ctrl[2], 1);
                if (p < CAP2)
                    surv[p] = ((unsigned long long)__float_as_uint(v) << 32)
                            | (uint32_t)(~(uint32_t)n);
            }
        }
        __syncthreads();
        if (tid < TOPK) {
            top_idx[tid] = -1;
            area_s[tid] = 0.0f;
            box_s[tid] = make_float4(-1.f, -1.f, -1.f, -1.f);
            cor_s[tid] = make_float4(0.f, 0.f, 0.f, 0.f);
        }
        const int S = min(ctrl[2], CAP2);
        __syncthreads();

        for (int i = tid; i < S; i += NTH) {
            unsigned long long me = surv[i];
            int rank = 0;
#pragma unroll 4
            for (int j = 0; j < S; ++j)
                rank += (surv[j] > me);
            if (rank < TOPK) {
                int idx = (int)(~(uint32_t)me);
                top_val[rank] = __uint_as_float((uint32_t)(me >> 32));
                top_idx[rank] = idx;
                float4 bx = *(const float4*)(loc + ((size_t)b * N_ + (size_t)idx) * 4);
                float hw = bx.z * 0.5f;
                float hh = bx.w * 0.5f;
                float4 cr = make_float4(bx.x - hw, bx.y - hh, bx.x + hw, bx.y + hh);
                box_s[rank] = bx;
                cor_s[rank] = cr;
                area_s[rank] = (cr.z - cr.x) * (cr.w - cr.y);
            }
        }
        __syncthreads();

        {
            bool v = (tid < TOPK) && (top_idx[tid] >= 0);
            unsigned long long m = __ballot(v);
            if (lane == 0) keepw[wv] = m;
        }

        {
            const int j = tid;
            float4 d = make_float4(0.f, 0.f, 0.f, 0.f);
            float  areaB = 0.0f;
            const bool jv = (j < TOPK);
            if (jv) { d = cor_s[j]; areaB = area_s[j]; }
#pragma unroll 2
            for (int i = 0; i < TOPK; ++i) {
                float4 a = cor_s[i];
                bool s = false;
                if (jv && j > i && top_idx[j] >= 0) {
                    float ltx = fmaxf(a.x, d.x), lty = fmaxf(a.y, d.y);
                    float rbx = fminf(a.z, d.z), rby = fminf(a.w, d.w);
                    float w  = fmaxf(rbx - ltx, 0.0f);
                    float h  = fmaxf(rby - lty, 0.0f);
                    float inter = w * h;
                    float U = (area_s[i] + areaB) - inter;
                    s = ((double)inter > M_IOU * (double)U);
                }
                unsigned long long m = __ballot(s);
                if (lane == 0) sup[i * SUPS + wv] = m;
            }
        }
        __syncthreads();

        if (tid < 64) {
            unsigned long long r0[4], r1[4], r2[4], r3[4];
#pragma unroll
            for (int w = 0; w < 4; ++w) {
                r0[w] = sup[(0 * 64 + tid) * SUPS + w];
                r1[w] = sup[(1 * 64 + tid) * SUPS + w];
                r2[w] = sup[(2 * 64 + tid) * SUPS + w];
                r3[w] = (192 + tid < TOPK) ? sup[(192 + tid) * SUPS + w] : 0ull;
            }
            unsigned long long k0 = keepw[0], k1 = keepw[1], k2 = keepw[2], k3 = keepw[3];
#define GREEDY_BLK(KW, RR)                                            \
            for (int ii = 0; ii < 64; ++ii) {                         \
                if ((KW >> ii) & 1ull) {                              \
                    k0 &= ~__shfl(RR[0], ii);                         \
                    k1 &= ~__shfl(RR[1], ii);                         \
                    k2 &= ~__shfl(RR[2], ii);                         \
                    k3 &= ~__shfl(RR[3], ii);                         \
                }                                                     \
            }
            GREEDY_BLK(k0, r0)
            GREEDY_BLK(k1, r1)
            GREEDY_BLK(k2, r2)
            GREEDY_BLK(k3, r3)
#undef GREEDY_BLK
            if (tid == 0) { keepw[0] = k0; keepw[1] = k1; keepw[2] = k2; keepw[3] = k3; }
        }
        __syncthreads();

        if (tid < TOPK) {
            const bool kp = (keepw[tid >> 6] >> (tid & 63)) & 1ull;
            float4 bx = box_s[tid];
            float* o = ostage + tid * 6;
            if (kp) {
                o[0] = (float)c;   o[1] = top_val[tid];
                o[2] = bx.x; o[3] = bx.y; o[4] = bx.z; o[5] = bx.w;
            } else {
                o[0] = -1.f; o[1] = -1.f; o[2] = -1.f;
                o[3] = -1.f; o[4] = -1.f; o[5] = -1.f;
            }
            out[(size_t)NBC * TOPK * 6 + (size_t)bc * TOPK + tid] = kp ? 1.0f : 0.0f;
        }
        __syncthreads();
        {
            float4* dst = (float4*)(out + (size_t)bc * TOPK * 6);
            const float4* src4 = (const float4*)ostage;
            for (int k = tid; k < TOPK * 6 / 4; k += NTH) dst[k] = src4[k];
        }
        __syncthreads();                           // LDS reuse across queue iters
    }
}

extern "C" void kernel_launch(void* const* d_in, const int* in_sizes, int n_in,
                              void* d_out, int out_size, void* d_ws, size_t ws_size,
                              hipStream_t stream) {
    (void)in_sizes; (void)n_in; (void)out_size;
    const float* loc  = (const float*)d_in[0];
    const float* conf = (const float*)d_in[1];
    float* out = (float*)d_out;

    const bool use_ws = (d_ws != nullptr) && (ws_size >= WS_NEED);
    int*   cnt  = (int*)((char*)d_ws + OFF_CNT);
    int*   qn   = (int*)((char*)d_ws + OFF_QN);
    int*   qbuf = (int*)((char*)d_ws + OFF_QBUF);
    uint2* cand = (uint2*)((char*)d_ws + OFF_CAND);

    if (use_ws) {
        hipLaunchKernelGGL(zero_hdr, dim3(16), dim3(NTH), 0, stream, cnt);
        hipLaunchKernelGGL(filter_k, dim3(B_ * NCHUNK), dim3(NTH), 0, stream,
                           conf, cnt, cand);
        hipLaunchKernelGGL(select_nms_k, dim3(NBC), dim3(NTH), 0, stream,
                           loc, cnt, cand, qn, qbuf, out);
        hipLaunchKernelGGL(rescue_k, dim3(64), dim3(NTH), 0, stream,
                           conf, loc, qn, qbuf, out, 1);
    } else {
        hipLaunchKernelGGL(rescue_k, dim3(NBC), dim3(NTH), 0, stream,
                           conf, loc, (const int*)nullptr, (const int*)nullptr,
                           out, 0);
    }
}

// Round 9
// 140.006 us; speedup vs baseline: 1.4889x; 1.4889x over previous
//
#include <hip/hip_runtime.h>
#include <cstdint>

#define B_      32
#define N_      32768
#define C_      81
#define NCLS    80      // last class (background) skipped
#define TOPK    200
#define CONF_T  0.01f
#define IOU_T   0.45f
#define NTH     256
#define NBC     (B_ * NCLS)          // 2560 (b,c) tasks

// exact IoU threshold compare without div:
// fl(inter/U) > 0.45f  <=>  (double)inter > M_IOU * (double)U   (U >= 0)
#define M_IOU   0.450000017881393432617187500

// ---- fast-path pre-filter: THR = 1 - 2^-6 = 0.984375 ----
#define THR_F    0.984375f
#define THR_BITS 0x3F7C0000u
#define CAP2     768

// filter blocking: one block per (b, 512-anchor slab)
#define ANCH_PB  512
#define NCHUNK   (N_ / ANCH_PB)      // 64
#define SLAB_F4  (ANCH_PB * C_ / 4)  // 10368 float4 per block
#define CAPB     1024

// slow-path histogram buckets over [0.5,1.0) via float bits
#define HBASE   129024
#define HBUCK   1024

// per-wave fast path: survivor cap
#define SCAP    256

// ws layout (bytes): cnt[NBC] | qn | qbuf[NBC] | cand[NBC][CAP2] u64 keys
#define OFF_CNT   0
#define OFF_QN    12288
#define OFF_QBUF  16384
#define OFF_CAND  32768
#define WS_NEED  (OFF_CAND + (size_t)NBC * CAP2 * 8)

#define WAVE_LGKM() asm volatile("s_waitcnt lgkmcnt(0)" ::: "memory")

__global__ void zero_hdr(int* __restrict__ p) {      // zeros cnt + qn
    int i = blockIdx.x * blockDim.x + threadIdx.x;
    if (i < 4096) p[i] = 0;
}

// ---- filter: at HBM roofline, frozen since R4 (flush now emits u64 keys) ----
__global__ __launch_bounds__(NTH) void filter_k(const float* __restrict__ conf,
                                                int* __restrict__ cnt,
                                                uint2* __restrict__ cand) {
    const int tid   = threadIdx.x;
    const int blk   = blockIdx.x;
    const int b     = blk >> 6;
    const int chunk = blk & (NCHUNK - 1);
    const uint32_t n0 = (uint32_t)chunk * ANCH_PB;
    const float4* slab = (const float4*)(conf + ((size_t)b * N_ + n0) * C_);

    __shared__ uint2 stage[CAPB];
    __shared__ int   lhist[NCLS];
    __shared__ int   lpos[NCLS];
    __shared__ int   gbase[NCLS];
    __shared__ int   ltot;

    for (int k = tid; k < NCLS; k += NTH) { lhist[k] = 0; lpos[k] = 0; }
    if (tid == 0) ltot = 0;
    __syncthreads();

    auto emit = [&](uint32_t e, float v) {
        uint32_t c = e % (uint32_t)C_;
        if (c < NCLS) {
            uint32_t nl = e / (uint32_t)C_;
            int q = atomicAdd(&ltot, 1);
            atomicAdd(&lhist[c], 1);
            if (q < CAPB)
                stage[q] = make_uint2(__float_as_uint(v), (c << 16) | nl);
        }
    };
    auto proc4 = [&](float4 x, uint32_t q) {
        if (x.x >= THR_F || x.y >= THR_F || x.z >= THR_F || x.w >= THR_F) {
            uint32_t e = q * 4u;
            if (x.x >= THR_F) emit(e + 0u, x.x);
            if (x.y >= THR_F) emit(e + 1u, x.y);
            if (x.z >= THR_F) emit(e + 2u, x.z);
            if (x.w >= THR_F) emit(e + 3u, x.w);
        }
    };

    uint32_t qb = (uint32_t)tid;
#pragma unroll 1
    for (int s = 0; s < 5; ++s, qb += 8 * NTH) {
        float4 v[8];
#pragma unroll
        for (int u = 0; u < 8; ++u) v[u] = slab[qb + u * NTH];
#pragma unroll
        for (int u = 0; u < 8; ++u) proc4(v[u], qb + u * NTH);
    }
    if (tid < SLAB_F4 - 5 * 8 * NTH) {
        uint32_t q = 5u * 8u * NTH + (uint32_t)tid;
        proc4(slab[q], q);
    }
    __syncthreads();

    const int tot = ltot;
    if (tot > CAPB) {
        for (int k = tid; k < NCLS; k += NTH)
            atomicAdd(&cnt[b * NCLS + k], CAP2 + 1);
        return;
    }
    if (tid < NCLS)
        gbase[tid] = atomicAdd(&cnt[b * NCLS + tid], lhist[tid]);
    __syncthreads();

    for (int q = tid; q < tot; q += NTH) {
        uint2 s = stage[q];
        uint32_t c  = s.y >> 16;
        uint32_t nl = s.y & 0xFFFFu;
        int pos = atomicAdd(&lpos[c], 1);
        int dst = gbase[c] + pos;
        if (dst < CAP2)   // u64 key layout: low word = ~anchor, high word = val bits
            cand[(size_t)(b * NCLS + c) * CAP2 + dst] = make_uint2(~(n0 + nl), s.x);
    }
}

// ================= one WAVE per task (R7 skeleton), zero barriers =================
// per-task LDS slice (7648 B, x4 waves = 30592 B/block -> 5 blocks/CU):
//  [0,2048)      surv u64[256]               } ostage f32[1200] overlays [0,4800)
//  [2048,5248)   cor  f4[200]  (hist int[256] overlays [2048,3072) pre-rank)
//  [5248,6048)   area f32[200]
//  [6048,6848)   tval f32[200]
//  [6848,7648)   tidx int[200]
#define TSL 7648

__global__ __launch_bounds__(NTH) void wave_select_k(const float* __restrict__ loc,
                                                     const int* __restrict__ cnt,
                                                     const unsigned long long* __restrict__ cand,
                                                     int* __restrict__ qn,
                                                     int* __restrict__ qbuf,
                                                     float* __restrict__ out) {
#pragma clang fp contract(off)
    const int tid  = threadIdx.x;
    const int lane = tid & 63;
    const int wv   = tid >> 6;
    const int bc   = blockIdx.x * 4 + wv;
    const int b    = bc / NCLS;
    const int c    = bc - b * NCLS;

    __shared__ __align__(16) char smem[4 * TSL];
    char* tb = smem + wv * TSL;
    unsigned long long* surv = (unsigned long long*)tb;
    float*  ostage = (float*)tb;                   // overlay (post-NMS)
    float4* cor_s  = (float4*)(tb + 2048);
    int*    hist   = (int*)(tb + 2048);            // overlay (pre-rank)
    float*  area_s = (float*)(tb + 5248);
    float*  tval   = (float*)(tb + 6048);
    int*    tidx   = (int*)(tb + 6848);

    const int M = cnt[bc];
    if (M < TOPK || M > CAP2) {                    // punt -> rescue queue
        if (lane == 0) { int p = atomicAdd(qn, 1); qbuf[p] = bc; }
        return;
    }
    const unsigned long long lmask_lt = (1ull << lane) - 1ull;

    // phase 1: candidate keys -> 12 regs/lane; zero hist
    const unsigned long long* src = cand + (size_t)bc * CAP2;
    unsigned long long key[12];
#pragma unroll
    for (int r = 0; r < 12; ++r) {
        int i = lane + 64 * r;
        key[r] = (i < M) ? src[i] : 0ull;
    }
    ((int4*)hist)[lane] = make_int4(0, 0, 0, 0);
    WAVE_LGKM();

    // phase 2: 256-bucket histogram (LDS atomics, this wave only)
#pragma unroll
    for (int r = 0; r < 12; ++r) {
        if (lane + 64 * r < M) {
            uint32_t k = ((uint32_t)(key[r] >> 32) - THR_BITS) >> 10;
            atomicAdd(&hist[k > 255u ? 255u : k], 1);
        }
    }
    WAVE_LGKM();

    // phase 3: in-wave suffix scan for cutoff bucket
    int cut;
    {
        int4 h = ((const int4*)hist)[63 - lane];
        int s3 = h.w, s2 = s3 + h.z, s1 = s2 + h.y, s0 = s1 + h.x;
        int tot = s0;
#pragma unroll
        for (int d = 1; d < 64; d <<= 1) {
            int t = __shfl_up(tot, d);
            if (lane >= d) tot += t;
        }
        int before = tot - s0;
        bool hit = (before < TOPK) && (before + s0 >= TOPK);
        int mycut = 0;
        if (hit) {
            int inner = (before + s3 >= TOPK) ? 3 : (before + s2 >= TOPK) ? 2
                      : (before + s1 >= TOPK) ? 1 : 0;
            mycut = (63 - lane) * 4 + inner;
        }
        unsigned long long hm = __ballot(hit);     // exactly one hit lane
        cut = __shfl(mycut, __ffsll(hm) - 1);
    }
    const uint32_t edge = THR_BITS + ((uint32_t)cut << 10);

    // phase 4: ballot-compaction of survivors (no atomics)
    int S = 0;
#pragma unroll
    for (int r = 0; r < 12; ++r) {
        bool take = (lane + 64 * r < M) && ((uint32_t)(key[r] >> 32) >= edge);
        unsigned long long m = __ballot(take);
        if (take) {
            int pos = S + (int)__popcll(m & lmask_lt);
            if (pos < SCAP) surv[pos] = key[r];
        }
        S += (int)__popcll(m);
    }
    if (S > SCAP) {                                // statistically never
        if (lane == 0) { int p = atomicAdd(qn, 1); qbuf[p] = bc; }
        return;
    }
    WAVE_LGKM();

    // phase 5: exact rank (u64 keys: val desc, idx asc) + fused loc gather
    unsigned long long me0 = surv[lane], me1 = surv[lane + 64], me2 = surv[lane + 128];
    unsigned long long me3 = (lane + 192 < S) ? surv[lane + 192] : ~0ull;
    int r0 = 0, r1 = 0, r2 = 0, r3 = 0;
    {
        const ulonglong2* sv2 = (const ulonglong2*)surv;
        const int Sh = S >> 1;
#pragma unroll 2
        for (int j2 = 0; j2 < Sh; ++j2) {
            ulonglong2 kj = sv2[j2];
            r0 += (kj.x > me0) + (kj.y > me0);
            r1 += (kj.x > me1) + (kj.y > me1);
            r2 += (kj.x > me2) + (kj.y > me2);
            r3 += (kj.x > me3) + (kj.y > me3);
        }
        if (S & 1) {
            unsigned long long kj = surv[S - 1];
            r0 += kj > me0; r1 += kj > me1; r2 += kj > me2; r3 += kj > me3;
        }
    }
    const float4* loc4 = (const float4*)(loc + ((size_t)b * N_) * 4);
    auto place = [&](unsigned long long me, int rk, bool valid) {
        if (valid && rk < TOPK) {
            int idx = (int)(~(uint32_t)me);
            float4 bx = loc4[idx];
            float hw = bx.z * 0.5f;
            float hh = bx.w * 0.5f;
            float4 cr = make_float4(bx.x - hw, bx.y - hh, bx.x + hw, bx.y + hh);
            cor_s[rk] = cr;
            area_s[rk] = (cr.z - cr.x) * (cr.w - cr.y);
            tval[rk] = __uint_as_float((uint32_t)(me >> 32));
            tidx[rk] = idx;
        }
    };
    place(me0, r0, true);
    place(me1, r1, true);
    place(me2, r2, true);
    place(me3, r3, lane + 192 < S);
    WAVE_LGKM();

    // phase 6: fused NMS — sequential greedy rows, cols in 4 ballot words.
    float4 d0 = cor_s[lane], d1 = cor_s[64 + lane], d2 = cor_s[128 + lane];
    float4 d3 = (lane < 8) ? cor_s[192 + lane] : d0;
    float ab0 = area_s[lane], ab1 = area_s[64 + lane], ab2 = area_s[128 + lane];
    float ab3 = (lane < 8) ? area_s[192 + lane] : 0.0f;
    unsigned long long k0 = ~0ull, k1 = ~0ull, k2 = ~0ull, k3 = (1ull << 8) - 1ull;

    auto iou_gt = [&](float4 a, float aa, float4 d, float ab) -> bool {
        float ltx = fmaxf(a.x, d.x), lty = fmaxf(a.y, d.y);
        float rbx = fminf(a.z, d.z), rby = fminf(a.w, d.w);
        float w = fmaxf(rbx - ltx, 0.0f);
        float h = fmaxf(rby - lty, 0.0f);
        float inter = w * h;
        float U = (aa + ab) - inter;
        return ((double)inter > M_IOU * (double)U);
    };

    float4 crn = cor_s[0];
    float  arn = area_s[0];
#define NMS_ROWS(W, KW, APPLY)                                            \
    for (int ii = 0; ii < 64; ++ii) {                                     \
        const int i = W * 64 + ii;                                        \
        if (i >= TOPK) break;                                             \
        float4 a = crn; float aa = arn;                                   \
        if (i + 1 < TOPK) { crn = cor_s[i + 1]; arn = area_s[i + 1]; }    \
        if ((KW >> ii) & 1ull) {                                          \
            unsigned long long gt = ~((2ull << ii) - 1ull);               \
            APPLY                                                         \
        }                                                                 \
    }
    NMS_ROWS(0, k0, {
        unsigned long long m0 = __ballot(iou_gt(a, aa, d0, ab0));
        unsigned long long m1 = __ballot(iou_gt(a, aa, d1, ab1));
        unsigned long long m2 = __ballot(iou_gt(a, aa, d2, ab2));
        unsigned long long m3 = __ballot(iou_gt(a, aa, d3, ab3));
        k0 &= ~(m0 & gt); k1 &= ~m1; k2 &= ~m2; k3 &= ~m3;
    })
    NMS_ROWS(1, k1, {
        unsigned long long m1 = __ballot(iou_gt(a, aa, d1, ab1));
        unsigned long long m2 = __ballot(iou_gt(a, aa, d2, ab2));
        unsigned long long m3 = __ballot(iou_gt(a, aa, d3, ab3));
        k1 &= ~(m1 & gt); k2 &= ~m2; k3 &= ~m3;
    })
    NMS_ROWS(2, k2, {
        unsigned long long m2 = __ballot(iou_gt(a, aa, d2, ab2));
        unsigned long long m3 = __ballot(iou_gt(a, aa, d3, ab3));
        k2 &= ~(m2 & gt); k3 &= ~m3;
    })
    NMS_ROWS(3, k3, {
        unsigned long long m3 = __ballot(iou_gt(a, aa, d3, ab3));
        k3 &= ~(m3 & gt);
    })
#undef NMS_ROWS

    // phase 7: stage rows in ostage (surv+cor dead), keep bits from registers
    const float cls_f = (float)c;
    float* kbase = out + (size_t)NBC * (TOPK * 6) + (size_t)bc * TOPK;
#pragma unroll
    for (int t = 0; t < 4; ++t) {
        int rk = lane + 64 * t;
        if (rk < TOPK) {
            unsigned long long kw = (t == 0) ? k0 : (t == 1) ? k1 : (t == 2) ? k2 : k3;
            bool kp = (kw >> lane) & 1ull;
            float4 bx = make_float4(-1.f, -1.f, -1.f, -1.f);
            float tv = -1.f, cf = -1.f;
            if (kp) { bx = loc4[tidx[rk]]; tv = tval[rk]; cf = cls_f; }
            float* o = ostage + rk * 6;
            o[0] = cf;   o[1] = tv;
            o[2] = bx.x; o[3] = bx.y; o[4] = bx.z; o[5] = bx.w;
            kbase[rk] = kp ? 1.0f : 0.0f;
        }
    }
    WAVE_LGKM();
    {   // coalesced flush: 300 float4
        float4* dst = (float4*)(out + (size_t)bc * (TOPK * 6));
        const float4* s4 = (const float4*)ostage;
#pragma unroll
        for (int t = 0; t < 5; ++t) {
            int k = lane + 64 * t;
            if (k < TOPK * 6 / 4) dst[k] = s4[k];
        }
    }
}

// ---- rescue: slow path only (punted / no-ws tasks), queue- or grid-driven ----
#define SUPS      5
#define SM_A      0
#define SM_B      8000
#define SM_BOX    8000
#define SM_COR    11200
#define SM_TVAL   14400
#define SM_TIDX   15200
#define SM_CTRL   16000
#define SM_KEEPW  16016
#define SM_AREA   16048
#define SM_TOTAL  16848

__global__ __launch_bounds__(NTH) void rescue_k(const float* __restrict__ conf,
                                                const float* __restrict__ loc,
                                                const int* __restrict__ qn,
                                                const int* __restrict__ qbuf,
                                                float* __restrict__ out,
                                                int qmode) {
#pragma clang fp contract(off)
    const int tid  = threadIdx.x;
    const int lane = tid & 63;
    const int wv   = tid >> 6;
    const int niter = qmode ? *qn : NBC;

    __shared__ __align__(16) char smem[SM_TOTAL];
    unsigned long long* surv = (unsigned long long*)(smem + SM_A);
    unsigned long long* sup  = (unsigned long long*)(smem + SM_A);
    float*  ostage = (float*)(smem + SM_A);
    int*    hist   = (int*)(smem + SM_B);
    float4* box_s  = (float4*)(smem + SM_BOX);
    float4* cor_s  = (float4*)(smem + SM_COR);
    float*  top_val = (float*)(smem + SM_TVAL);
    int*    top_idx = (int*)(smem + SM_TIDX);
    int*    ctrl   = (int*)(smem + SM_CTRL);
    unsigned long long* keepw = (unsigned long long*)(smem + SM_KEEPW);
    float*  area_s = (float*)(smem + SM_AREA);

    for (int qi = blockIdx.x; qi < niter; qi += gridDim.x) {
        const int bc = qmode ? qbuf[qi] : qi;
        const int b  = bc / NCLS;
        const int c  = bc - b * NCLS;

        for (int k = tid; k < HBUCK; k += NTH) hist[k] = 0;
        if (tid == 0) ctrl[2] = 0;
        __syncthreads();
        const float* col = conf + ((size_t)b * N_) * C_ + c;
        for (int n = tid; n < N_; n += NTH) {
            float v = col[(size_t)n * C_];
            if (v >= 0.5f) {
                int bkt = (int)(__float_as_uint(v) >> 13) - HBASE;
                atomicAdd(&hist[min(bkt, HBUCK - 1)], 1);
            }
        }
        __syncthreads();
        if (tid == 0) {
            int acc = 0, cut = -1;
            for (int k = HBUCK - 1; k >= 0; --k) {
                acc += hist[k];
                if (acc >= TOPK) { cut = k; break; }
            }
            ctrl[1] = cut;
        }
        __syncthreads();
        const int   cutv = ctrl[1];
        const float vcut = (cutv >= 0) ? __uint_as_float((uint32_t)(HBASE + cutv) << 13)
                                       : CONF_T;
        for (int n = tid; n < N_; n += NTH) {
            float v = col[(size_t)n * C_];
            bool take = (cutv >= 0) ? (v >= vcut) : (v > CONF_T);
            if (take) {
                int p = atomicAdd(&ctrl[2], 1);
                if (p < CAP2)
                    surv[p] = ((unsigned long long)__float_as_uint(v) << 32)
                            | (uint32_t)(~(uint32_t)n);
            }
        }
        __syncthreads();
        if (tid < TOPK) {
            top_idx[tid] = -1;
            area_s[tid] = 0.0f;
            box_s[tid] = make_float4(-1.f, -1.f, -1.f, -1.f);
            cor_s[tid] = make_float4(0.f, 0.f, 0.f, 0.f);
        }
        const int S = min(ctrl[2], CAP2);
        __syncthreads();

        for (int i = tid; i < S; i += NTH) {
            unsigned long long me = surv[i];
            int rank = 0;
#pragma unroll 4
            for (int j = 0; j < S; ++j)
                rank += (surv[j] > me);
            if (rank < TOPK) {
                int idx = (int)(~(uint32_t)me);
                top_val[rank] = __uint_as_float((uint32_t)(me >> 32));
                top_idx[rank] = idx;
                float4 bx = *(const float4*)(loc + ((size_t)b * N_ + (size_t)idx) * 4);
                float hw = bx.z * 0.5f;
                float hh = bx.w * 0.5f;
                float4 cr = make_float4(bx.x - hw, bx.y - hh, bx.x + hw, bx.y + hh);
                box_s[rank] = bx;
                cor_s[rank] = cr;
                area_s[rank] = (cr.z - cr.x) * (cr.w - cr.y);
            }
        }
        __syncthreads();

        {
            bool v = (tid < TOPK) && (top_idx[tid] >= 0);
            unsigned long long m = __ballot(v);
            if (lane == 0) keepw[wv] = m;
        }

        {
            const int j = tid;
            float4 d = make_float4(0.f, 0.f, 0.f, 0.f);
            float  areaB = 0.0f;
            const bool jv = (j < TOPK);
            if (jv) { d = cor_s[j]; areaB = area_s[j]; }
#pragma unroll 2
            for (int i = 0; i < TOPK; ++i) {
                float4 a = cor_s[i];
                bool s = false;
                if (jv && j > i && top_idx[j] >= 0) {
                    float ltx = fmaxf(a.x, d.x), lty = fmaxf(a.y, d.y);
                    float rbx = fminf(a.z, d.z), rby = fminf(a.w, d.w);
                    float w  = fmaxf(rbx - ltx, 0.0f);
                    float h  = fmaxf(rby - lty, 0.0f);
                    float inter = w * h;
                    float U = (area_s[i] + areaB) - inter;
                    s = ((double)inter > M_IOU * (double)U);
                }
                unsigned long long m = __ballot(s);
                if (lane == 0) sup[i * SUPS + wv] = m;
            }
        }
        __syncthreads();

        if (tid < 64) {
            unsigned long long r0[4], r1[4], r2[4], r3[4];
#pragma unroll
            for (int w = 0; w < 4; ++w) {
                r0[w] = sup[(0 * 64 + tid) * SUPS + w];
                r1[w] = sup[(1 * 64 + tid) * SUPS + w];
                r2[w] = sup[(2 * 64 + tid) * SUPS + w];
                r3[w] = (192 + tid < TOPK) ? sup[(192 + tid) * SUPS + w] : 0ull;
            }
            unsigned long long k0 = keepw[0], k1 = keepw[1], k2 = keepw[2], k3 = keepw[3];
#define GREEDY_BLK(KW, RR)                                            \
            for (int ii = 0; ii < 64; ++ii) {                         \
                if ((KW >> ii) & 1ull) {                              \
                    k0 &= ~__shfl(RR[0], ii);                         \
                    k1 &= ~__shfl(RR[1], ii);                         \
                    k2 &= ~__shfl(RR[2], ii);                         \
                    k3 &= ~__shfl(RR[3], ii);                         \
                }                                                     \
            }
            GREEDY_BLK(k0, r0)
            GREEDY_BLK(k1, r1)
            GREEDY_BLK(k2, r2)
            GREEDY_BLK(k3, r3)
#undef GREEDY_BLK
            if (tid == 0) { keepw[0] = k0; keepw[1] = k1; keepw[2] = k2; keepw[3] = k3; }
        }
        __syncthreads();

        if (tid < TOPK) {
            const bool kp = (keepw[tid >> 6] >> (tid & 63)) & 1ull;
            float4 bx = box_s[tid];
            float* o = ostage + tid * 6;
            if (kp) {
                o[0] = (float)c;   o[1] = top_val[tid];
                o[2] = bx.x; o[3] = bx.y; o[4] = bx.z; o[5] = bx.w;
            } else {
                o[0] = -1.f; o[1] = -1.f; o[2] = -1.f;
                o[3] = -1.f; o[4] = -1.f; o[5] = -1.f;
            }
            out[(size_t)NBC * TOPK * 6 + (size_t)bc * TOPK + tid] = kp ? 1.0f : 0.0f;
        }
        __syncthreads();
        {
            float4* dst = (float4*)(out + (size_t)bc * TOPK * 6);
            const float4* src4 = (const float4*)ostage;
            for (int k = tid; k < TOPK * 6 / 4; k += NTH) dst[k] = src4[k];
        }
        __syncthreads();                           // LDS reuse across queue iters
    }
}

extern "C" void kernel_launch(void* const* d_in, const int* in_sizes, int n_in,
                              void* d_out, int out_size, void* d_ws, size_t ws_size,
                              hipStream_t stream) {
    (void)in_sizes; (void)n_in; (void)out_size;
    const float* loc  = (const float*)d_in[0];
    const float* conf = (const float*)d_in[1];
    float* out = (float*)d_out;

    const bool use_ws = (d_ws != nullptr) && (ws_size >= WS_NEED);
    int*   cnt  = (int*)((char*)d_ws + OFF_CNT);
    int*   qn   = (int*)((char*)d_ws + OFF_QN);
    int*   qbuf = (int*)((char*)d_ws + OFF_QBUF);
    uint2* cand = (uint2*)((char*)d_ws + OFF_CAND);

    if (use_ws) {
        hipLaunchKernelGGL(zero_hdr, dim3(16), dim3(NTH), 0, stream, cnt);
        hipLaunchKernelGGL(filter_k, dim3(B_ * NCHUNK), dim3(NTH), 0, stream,
                           conf, cnt, cand);
        hipLaunchKernelGGL(wave_select_k, dim3(NBC / 4), dim3(NTH), 0, stream,
                           loc, cnt, (const unsigned long long*)cand, qn, qbuf, out);
        hipLaunchKernelGGL(rescue_k, dim3(64), dim3(NTH), 0, stream,
                           conf, loc, qn, qbuf, out, 1);
    } else {
        hipLaunchKernelGGL(rescue_k, dim3(NBC), dim3(NTH), 0, stream,
                           conf, loc, (const int*)nullptr, (const int*)nullptr,
                           out, 0);
    }
}